// Round 9
// baseline (305.222 us; speedup 1.0000x reference)
//
#include <hip/hip_runtime.h>

// MultiHeadAttention: B=4 T=2048 C=1024 H=16 D=64, fp32 in/out, bf16 MFMA internally.
//
// Pipeline (all on `stream`):
//   1. prep_kernel:      cast x -> bf16 AND Wq/Wk/Wv/Wp -> W^T bf16 (merged, R11)
//   2. gemm_qkv:         Q/K = xb @ W^T + b (bf16); Q pre-scaled by
//                        0.125*log2(e) (R7); V written TRANSPOSED as Vt
//                        [b,h,d,t] (kt-permuted, R6); XCD-clustered grid (R10)
//   3. attn_kernel:      flash attention, operand-swapped, 64 q/wave (R7),
//                        XCD-clustered grid (R9), KVBLK=64 double-buffered
//                        LDS with ONE barrier per chunk (R13)
//   4. gemm_proj:        out = attn @ Wp^T + bp, fp32; 128x64 tiles (R12)
//
// R6: P LDS round-trip eliminated via bf16x2 pack + v_permlane16_swap_b32;
//     V^T stored kt-permuted: pos = (quad&1)<<5 | (((quad>>1)<<1|(mt&1))<<3)
//     | ((mt>>1)<<2) (+r) within each 64-aligned t-block.
// R7: 64 q/wave attn (4 q-sets share K/V frags); logit scale folded into Q.
// R9: XCD-clustered attn grid (FETCH 139->24.6MB) + raw barriers.
// R11 (reverted): KVBLK=128 dbuf doubled staged regs + code body: VGPR 164,
//     occ 10.6%, 114us. R12 setprio on PV (reverted): 85.5->89.1us —
//     confirms T5 hurts barrier-lockstep kernels (m190).
// R12: proj 128x64 tiles (grid 1024 = 4 blocks/CU; was 2/CU): kept.
// R13: single-barrier double-buffer at KVBLK=64 — R11's goal without its
//     costs. Per chunk: gload(c+1) [16 VGPR, same as old prefetch],
//     compute(buf[c&1]) [single body], stage(buf[(c+1)&1]), lgkm+barrier.
//     WAR-safe: stage(c) overwrites the buffer read in c-1; all waves passed
//     the end-of-(c-1) barrier only after their compute(c-1) reads. vmcnt
//     wait for gload lands at stage's ds_write, hidden under ~3400cyc of
//     compute. Barrier clusters 64 -> 33.

#define B_ 4
#define T_ 2048
#define C_ 1024
#define H_ 16
#define D_ 64

// 0.125 * log2(e): attention scale folded into Q at projection time (R7b).
#define QSCALE 0.18033688011112042f

typedef float  f32x4  __attribute__((ext_vector_type(4)));
typedef __bf16 bf16x8 __attribute__((ext_vector_type(8)));
typedef __bf16 bf16x4 __attribute__((ext_vector_type(4)));
typedef __bf16 bf16x2 __attribute__((ext_vector_type(2)));
typedef unsigned uint2v __attribute__((ext_vector_type(2)));

typedef const __attribute__((address_space(1))) void gv_t;
typedef __attribute__((address_space(3))) void lds_t;

__device__ __forceinline__ void async_load16(const void* g, void* l) {
  __builtin_amdgcn_global_load_lds((gv_t*)g, (lds_t*)l, 16, 0, 0);
}

__device__ __forceinline__ float fast_exp2(float x) {
#if __has_builtin(__builtin_amdgcn_exp2f)
  return __builtin_amdgcn_exp2f(x);
#else
  return exp2f(x);
#endif
}

// v_permlane16_swap_b32: newA rows = [A0,B0,A2,B2], newB rows = [A1,B1,A3,B3]
__device__ __forceinline__ void pl16_swap(unsigned& a, unsigned& b) {
#if __has_builtin(__builtin_amdgcn_permlane16_swap)
  uint2v r = __builtin_amdgcn_permlane16_swap(a, b, false, false);
  a = r[0];
  b = r[1];
#else
  asm("v_permlane16_swap_b32 %0, %1" : "+v"(a), "+v"(b));
#endif
}

// ---------------- merged prep: cast x (blocks 0..4095) + W^T (4096..5119)
__global__ __launch_bounds__(256) void prep_kernel(
    const float* __restrict__ x, __bf16* __restrict__ xb,
    const float* __restrict__ W0, const float* __restrict__ W1,
    const float* __restrict__ W2, const float* __restrict__ W3,
    __bf16* __restrict__ wt) {
  __shared__ __align__(16) __bf16 sT[64][72];
  int l = blockIdx.x;
  int tid = threadIdx.x;
  if (l < 4096) {
    int i = (l * 256 + tid) * 8;  // exact: 4096*256*8 == B*T*C
    float4 a = *(const float4*)(x + i);
    float4 b = *(const float4*)(x + i + 4);
    bf16x8 o;
    o[0] = (__bf16)a.x; o[1] = (__bf16)a.y; o[2] = (__bf16)a.z; o[3] = (__bf16)a.w;
    o[4] = (__bf16)b.x; o[5] = (__bf16)b.y; o[6] = (__bf16)b.z; o[7] = (__bf16)b.w;
    *(bf16x8*)(xb + i) = o;
    return;
  }
  int t = l - 4096;                 // 0..1023
  int z = t >> 8;                   // 0..3
  int k0 = ((t >> 4) & 15) * 64;
  int n0 = (t & 15) * 64;
  const float* W = (z == 0) ? W0 : (z == 1) ? W1 : (z == 2) ? W2 : W3;
  __bf16* o = wt + (size_t)z * (C_ * C_);
#pragma unroll
  for (int i = 0; i < 4; i++) {
    int s = tid + i * 256;
    int kr = s >> 4, nc = (s & 15) * 4;
    float4 v = *(const float4*)&W[(size_t)(k0 + kr) * C_ + n0 + nc];
    bf16x4 tt;
    tt[0] = (__bf16)v.x; tt[1] = (__bf16)v.y; tt[2] = (__bf16)v.z; tt[3] = (__bf16)v.w;
    *(bf16x4*)&sT[kr][nc] = tt;
  }
  __syncthreads();
#pragma unroll
  for (int i = 0; i < 2; i++) {
    int s = tid + i * 256;
    int nr = s >> 3, kc = (s & 7) * 8;
    bf16x8 ov;
#pragma unroll
    for (int j = 0; j < 8; j++) ov[j] = sT[kc + j][nr];
    *(bf16x8*)&o[(size_t)(n0 + nr) * C_ + k0 + kc] = ov;
  }
}

// ------------------------------------------------ m97-style GEMM, B^T input
// C[M,BNtot] = (A[M,K](bf16) @ Bt[.,K](bf16)^T + bias) * scale
// Tile 128 x BN (BN = 128 or 64). EPI 0: row-major OutT. EPI 1: V-transpose
// into Vt[b,h,d,t] with the R6 kt-permutation (BN=128 only).
template <typename OutT, int EPI, int BN>
__device__ __forceinline__ void gemm_body(
    const __bf16* __restrict__ A, const __bf16* __restrict__ Bt,
    const float* __restrict__ bias, OutT* __restrict__ C, int N, int K,
    float scale, int m0, int n0) {
  __shared__ __align__(16) __bf16 sA[128 * 32];  // no pad: global_load_lds needs contig
  __shared__ __align__(16) __bf16 sB[BN * 32];
  constexpr int NTW = BN / 32;       // n-tiles per wave (4 or 2)
  constexpr int NBU = BN * 4 / 256;  // B staging units per thread (2 or 1)
  int tid = threadIdx.x, lane = tid & 63, wave = tid >> 6;
  int lr = lane & 15, quad = lane >> 4;
  int wm = (wave & 1) * 64, wn = (wave >> 1) * (BN / 2);

  const f32x4 zero = {0.f, 0.f, 0.f, 0.f};
  f32x4 acc[4][NTW];
#pragma unroll
  for (int i = 0; i < 4; i++)
#pragma unroll
    for (int j = 0; j < NTW; j++) acc[i][j] = zero;

  for (int k0 = 0; k0 < K; k0 += 32) {
    __syncthreads();
#pragma unroll
    for (int i = 0; i < 2; i++) {
      int s = tid + i * 256;
      int r = s >> 2, c8 = (s & 3) * 8;
      async_load16(A + (size_t)(m0 + r) * K + k0 + c8, &sA[s * 8]);
    }
#pragma unroll
    for (int i = 0; i < NBU; i++) {
      int s = tid + i * 256;
      int r = s >> 2, c8 = (s & 3) * 8;
      async_load16(Bt + (size_t)(n0 + r) * K + k0 + c8, &sB[s * 8]);
    }
    __syncthreads();
    bf16x8 af[4], bfr[NTW];
#pragma unroll
    for (int mt = 0; mt < 4; mt++)
      af[mt] = *(const bf16x8*)&sA[(wm + mt * 16 + lr) * 32 + quad * 8];
#pragma unroll
    for (int nt = 0; nt < NTW; nt++)
      bfr[nt] = *(const bf16x8*)&sB[(wn + nt * 16 + lr) * 32 + quad * 8];
#pragma unroll
    for (int mt = 0; mt < 4; mt++)
#pragma unroll
      for (int nt = 0; nt < NTW; nt++)
        acc[mt][nt] = __builtin_amdgcn_mfma_f32_16x16x32_bf16(
            af[mt], bfr[nt], acc[mt][nt], 0, 0, 0);
  }
  // C/D layout: col=lane&15 (n), row=mt*16+quad*4+reg (m)  [m89/m91]
  if (EPI == 0) {
#pragma unroll
    for (int mt = 0; mt < 4; mt++) {
#pragma unroll
      for (int nt = 0; nt < NTW; nt++) {
        int n = n0 + wn + nt * 16 + lr;
        float bv = bias[n];
#pragma unroll
        for (int r = 0; r < 4; r++) {
          int m = m0 + wm + mt * 16 + quad * 4 + r;
          C[(size_t)m * N + n] = (OutT)((acc[mt][nt][r] + bv) * scale);
        }
      }
    }
  } else {
    // V^T: Vt[(b*16+h)*64+d][t_permuted] = V[t][n=h*64+d] + bias
    int bb = m0 >> 11;               // m0 / T_ (tiles never straddle batches)
    int mloc0 = (m0 & (T_ - 1)) + wm;  // 64-aligned
    __bf16* Ct = (__bf16*)C;
#pragma unroll
    for (int mt = 0; mt < 4; mt++) {
      int pos = ((quad & 1) << 5) | ((((quad >> 1) << 1) | (mt & 1)) << 3) |
                ((mt >> 1) << 2);
#pragma unroll
      for (int nt = 0; nt < NTW; nt++) {
        int n = n0 + wn + nt * 16 + lr;
        float bv = bias[n];
        bf16x4 ov;
#pragma unroll
        for (int r = 0; r < 4; r++) ov[r] = (__bf16)(acc[mt][nt][r] + bv);
        *(bf16x4*)&Ct[((size_t)bb * C_ + n) * T_ + mloc0 + pos] = ov;
      }
    }
  }
}

// R10: 1-D grid 1536. xcd = l&7 owns 8 m-rows x 8 n-tiles per matrix z.
__global__ __launch_bounds__(256) void gemm_qkv_kernel(
    const __bf16* __restrict__ A, const __bf16* __restrict__ WT,
    const float* __restrict__ b0, const float* __restrict__ b1,
    const float* __restrict__ b2, __bf16* __restrict__ qkbase,
    __bf16* __restrict__ Vt) {
  int l = blockIdx.x;
  int xcd = l & 7;
  int idx = l >> 3;        // 0..191
  int z = idx >> 6;        // 0..2
  int rem = idx & 63;      // 0..63
  int m0 = (xcd * 8 + (rem >> 3)) * 128;
  int n0 = (rem & 7) * 128;
  if (z == 2) {
    gemm_body<__bf16, 1, 128>(A, WT + (size_t)2 * C_ * C_, b2, Vt, C_, C_,
                              1.0f, m0, n0);
  } else {
    const float* bias = (z == 0) ? b0 : b1;
    float scale = (z == 0) ? QSCALE : 1.0f;  // R7b: fold attn scale into Q
    gemm_body<__bf16, 0, 128>(A, WT + (size_t)z * C_ * C_, bias,
                              qkbase + (size_t)z * (B_ * T_) * C_, C_, C_,
                              scale, m0, n0);
  }
}

// R12: 128x64 tiles, grid 1024 = 4 blocks/CU (was 512 = 2/CU).
__global__ __launch_bounds__(256) void gemm_proj_kernel(
    const __bf16* __restrict__ A, const __bf16* __restrict__ Bt,
    const float* __restrict__ bias, float* __restrict__ C) {
  int l = blockIdx.x;
  int xcd = l & 7;
  int idx = l >> 3;        // 0..127
  int m0 = (xcd * 8 + (idx >> 4)) * 128;  // 64 m-tiles
  int n0 = (idx & 15) * 64;               // 16 n-tiles of 64
  gemm_body<float, 0, 64>(A, Bt, bias, C, C_, C_, 1.0f, m0, n0);
}

// ----------------- attention, operand-swapped, no-max softmax, 64 q / wave
// grid 512 (1-D, XCD-clustered), 256 thr. KVBLK=64 double-buffered, ONE
// barrier per chunk (R13). No setprio (R12 revert).
__global__ __launch_bounds__(256) void attn_kernel(
    const __bf16* __restrict__ Q, const __bf16* __restrict__ K,
    const __bf16* __restrict__ Vt, __bf16* __restrict__ O) {
  __shared__ __align__(16) __bf16 sK[2][64 * 72];   // [buf][kt][d]
  __shared__ __align__(16) __bf16 sV[2][64 * 72];   // [buf][d][kt_permuted]
  int tid = threadIdx.x, wave = tid >> 6, lane = tid & 63;
  int lr = lane & 15, quad = lane >> 4;
  // R9b: XCD-clustered decode. l%8 = XCD class -> 8 bh per XCD.
  int l = blockIdx.x;
  int bh = (l & 7) * 8 + ((l >> 3) & 7);
  int xbq = l >> 6;  // 0..7
  int b = bh >> 4, h = bh & 15;
  int qw = xbq * 256 + wave * 64;

  bf16x8 aq[4][2];
#pragma unroll
  for (int s = 0; s < 4; s++) {
    const __bf16* qp =
        Q + ((size_t)(b * T_ + qw + s * 16 + lr)) * C_ + h * D_ + quad * 8;
    aq[s][0] = *(const bf16x8*)qp;
    aq[s][1] = *(const bf16x8*)(qp + 32);
  }

  bf16x8 onesf;
#pragma unroll
  for (int j = 0; j < 8; j++) onesf[j] = (__bf16)1.0f;

  const f32x4 zero = {0.f, 0.f, 0.f, 0.f};
  f32x4 accO[4][4];
  f32x4 accL[4] = {zero, zero, zero, zero};
#pragma unroll
  for (int s = 0; s < 4; s++)
#pragma unroll
    for (int d = 0; d < 4; d++) accO[s][d] = zero;

  int srow[2], sc8[2];
#pragma unroll
  for (int i = 0; i < 2; i++) {
    int s = tid + i * 256;
    srow[i] = s >> 3;
    sc8[i] = (s & 7) * 8;
  }

  bf16x8 kreg[2], vreg[2];
  auto gload = [&](int k0) {
#pragma unroll
    for (int i = 0; i < 2; i++) {
      kreg[i] = *(const bf16x8*)(K + ((size_t)(b * T_ + k0 + srow[i])) * C_ + h * D_ + sc8[i]);
      vreg[i] = *(const bf16x8*)(Vt + ((size_t)(bh * D_ + srow[i])) * T_ + k0 + sc8[i]);
    }
  };
  auto stage = [&](int buf) {
#pragma unroll
    for (int i = 0; i < 2; i++) {
      *(bf16x8*)&sK[buf][srow[i] * 72 + sc8[i]] = kreg[i];
      *(bf16x8*)&sV[buf][srow[i] * 72 + sc8[i]] = vreg[i];
    }
  };

  // prologue: chunk 0 into buf 0
  gload(0);
  stage(0);
  __builtin_amdgcn_sched_barrier(0);
  asm volatile("s_waitcnt lgkmcnt(0)" ::: "memory");
  __builtin_amdgcn_s_barrier();
  __builtin_amdgcn_sched_barrier(0);

  const int NC = T_ / 64;  // 32 chunks
  for (int c = 0; c < NC; c++) {
    int buf = c & 1;
    if (c + 1 < NC) gload((c + 1) * 64);  // latency hides under compute
    const __bf16* sKh = &sK[buf][0];
    const __bf16* sVh = &sV[buf][0];

    // K fragments: 8 LDS reads per chunk, shared by all 4 q-sets (R7a).
    bf16x8 bkf[4][2];
#pragma unroll
    for (int nt = 0; nt < 4; nt++) {
      bkf[nt][0] = *(const bf16x8*)&sKh[(nt * 16 + lr) * 72 + quad * 8];
      bkf[nt][1] = *(const bf16x8*)&sKh[(nt * 16 + lr) * 72 + 32 + quad * 8];
    }

    bf16x8 bpA[4], bpB[4];
#pragma unroll
    for (int s = 0; s < 4; s++) {
      unsigned pw[4][2];
#pragma unroll
      for (int nt = 0; nt < 4; nt++) {
        f32x4 z = zero;
        z = __builtin_amdgcn_mfma_f32_16x16x32_bf16(bkf[nt][0], aq[s][0], z, 0, 0, 0);
        z = __builtin_amdgcn_mfma_f32_16x16x32_bf16(bkf[nt][1], aq[s][1], z, 0, 0, 0);
        union { bf16x2 h2; unsigned u; } t0, t1;
        t0.h2[0] = (__bf16)fast_exp2(z[0]);
        t0.h2[1] = (__bf16)fast_exp2(z[1]);
        t1.h2[0] = (__bf16)fast_exp2(z[2]);
        t1.h2[1] = (__bf16)fast_exp2(z[3]);
        pw[nt][0] = t0.u;
        pw[nt][1] = t1.u;
      }
      unsigned a0 = pw[0][0], b0 = pw[1][0]; pl16_swap(a0, b0);
      unsigned a1 = pw[0][1], b1 = pw[1][1]; pl16_swap(a1, b1);
      unsigned a2 = pw[2][0], b2 = pw[3][0]; pl16_swap(a2, b2);
      unsigned a3 = pw[2][1], b3 = pw[3][1]; pl16_swap(a3, b3);
      union { unsigned u[4]; bf16x8 v; } pA, pB;
      pA.u[0] = a0; pA.u[1] = a1; pA.u[2] = a2; pA.u[3] = a3;
      pB.u[0] = b0; pB.u[1] = b1; pB.u[2] = b2; pB.u[3] = b3;
      bpA[s] = pA.v;
      bpB[s] = pB.v;
      accL[s] = __builtin_amdgcn_mfma_f32_16x16x32_bf16(onesf, bpA[s], accL[s], 0, 0, 0);
      accL[s] = __builtin_amdgcn_mfma_f32_16x16x32_bf16(onesf, bpB[s], accL[s], 0, 0, 0);
    }
#pragma unroll
    for (int dt = 0; dt < 4; dt++) {
      bf16x8 av0 = *(const bf16x8*)&sVh[(dt * 16 + lr) * 72 + quad * 8];
      bf16x8 av1 = *(const bf16x8*)&sVh[(dt * 16 + lr) * 72 + 32 + quad * 8];
#pragma unroll
      for (int s = 0; s < 4; s++) {
        accO[s][dt] = __builtin_amdgcn_mfma_f32_16x16x32_bf16(av0, bpA[s], accO[s][dt], 0, 0, 0);
        accO[s][dt] = __builtin_amdgcn_mfma_f32_16x16x32_bf16(av1, bpB[s], accO[s][dt], 0, 0, 0);
      }
    }

    if (c + 1 < NC) {
      stage(buf ^ 1);  // WAR-safe: readers of buf^1 passed end-of-(c-1) barrier
      __builtin_amdgcn_sched_barrier(0);
      asm volatile("s_waitcnt lgkmcnt(0)" ::: "memory");
      __builtin_amdgcn_s_barrier();
      __builtin_amdgcn_sched_barrier(0);
    }
  }

#pragma unroll
  for (int s = 0; s < 4; s++) {
    float inv = 1.0f / accL[s][0];
    __bf16* op =
        O + ((size_t)(b * T_ + qw + s * 16 + lr)) * C_ + h * D_ + quad * 4;
#pragma unroll
    for (int dt = 0; dt < 4; dt++) {
      bf16x4 ov;
#pragma unroll
      for (int r = 0; r < 4; r++) ov[r] = (__bf16)(accO[s][dt][r] * inv);
      *(bf16x4*)&op[dt * 16] = ov;
    }
  }
}

// ------------------------------------------------------------------ launch
extern "C" void kernel_launch(void* const* d_in, const int* in_sizes, int n_in,
                              void* d_out, int out_size, void* d_ws, size_t ws_size,
                              hipStream_t stream) {
  const float* x  = (const float*)d_in[0];
  const float* Wq = (const float*)d_in[1];
  const float* bq = (const float*)d_in[2];
  const float* Wk = (const float*)d_in[3];
  const float* bk = (const float*)d_in[4];
  const float* Wv = (const float*)d_in[5];
  const float* bv = (const float*)d_in[6];
  const float* Wp = (const float*)d_in[7];
  const float* bp = (const float*)d_in[8];
  float* out = (float*)d_out;

  char* ws = (char*)d_ws;
  const size_t MB = 1024 * 1024;
  __bf16* xb    = (__bf16*)(ws + 0 * MB);   // 16 MB
  __bf16* WT    = (__bf16*)(ws + 16 * MB);  // 8 MB
  __bf16* Qb    = (__bf16*)(ws + 24 * MB);  // Q 16 MB (pre-scaled by QSCALE)
  __bf16* Kb    = Qb + (size_t)(B_ * T_) * C_;   // K 16 MB
  __bf16* Vt    = Kb + (size_t)(B_ * T_) * C_;   // V^T 16 MB (R6-permuted)
  __bf16* attnb = (__bf16*)(ws + 72 * MB);  // 16 MB; total 88 MB
  __bf16* WpT   = WT + (size_t)3 * C_ * C_;

  prep_kernel<<<dim3(5120), dim3(256), 0, stream>>>(x, xb, Wq, Wk, Wv, Wp, WT);
  gemm_qkv_kernel<<<dim3(1536), dim3(256), 0, stream>>>(xb, WT, bq, bk, bv, Qb, Vt);
  attn_kernel<<<dim3(512), dim3(256), 0, stream>>>(Qb, Kb, Vt, attnb);
  gemm_proj_kernel<<<dim3(1024), dim3(256), 0, stream>>>(attnb, WpT, bp, out);
}

// Round 10
// 301.922 us; speedup vs baseline: 1.0109x; 1.0109x over previous
//
#include <hip/hip_runtime.h>

// MultiHeadAttention: B=4 T=2048 C=1024 H=16 D=64, fp32 in/out, bf16 MFMA internally.
//
// Pipeline (all on `stream`):
//   1. prep_kernel:      cast x -> bf16 AND Wq/Wk/Wv/Wp -> W^T bf16 (merged)
//   2. gemm_qkv:         Q/K = xb @ W^T + b (bf16); Q pre-scaled by
//                        0.125*log2(e) (R7); V written TRANSPOSED as Vt
//                        [b,h,d,t] (kt-permuted, R6); XCD-clustered grid (R10)
//   3. attn_kernel<2>:   flash attention, operand-swapped, 64 q/wave (R7),
//                        R9 two-barrier body, SPLIT-KT x2 (R14): grid 1024 =
//                        4 blocks/CU (was 2); unnormalized f32 partials
//   3b. attn_combine:    out = (O0+O1)/(l0+l1) -> bf16 attnb (~14us, mem-bound)
//   4. gemm_proj:        out = attn @ Wp^T + bp, fp32; 128x64 tiles (R12)
//
// R6: P LDS round-trip eliminated via bf16x2 pack + v_permlane16_swap_b32;
//     V^T stored kt-permuted: pos = (quad&1)<<5 | (((quad>>1)<<1|(mt&1))<<3)
//     | ((mt>>1)<<2) (+r) within each 64-aligned t-block.
// R7: 64 q/wave attn (4 q-sets share K/V frags); logit scale folded into Q.
// R9: XCD-clustered attn grid + raw two-barrier protocol (VGPR 116 = the
//     local optimum; R11/R13 barrier-reduction attempts both blew VGPR to
//     144-164 and regressed to 114-122us. R12 setprio also regressed. All
//     reverted.)
// R12: proj 128x64 tiles (grid 1024 = 4 blocks/CU): kept (~+4us).
// R14: attn occupancy was grid-limited: 512 blocks = 2/CU while VGPR 116 /
//     LDS 18KB admit 4/CU; per-SIMD VALU issue only ~23%/wave -> stall-bound
//     with idle slots. Split kt in half (flash-decoding): no-max softmax
//     partials combine EXACTLY: l=l0+l1, O=O0+O1, out=(O0+O1)/(l0+l1).
//     Main kernel grid 1024 (same per-wave body), f32 partials to ws+88MB
//     (64MB O + 1MB l; runtime fallback to single-pass if ws too small);
//     combine kernel is memory-bound (~80MB).

#define B_ 4
#define T_ 2048
#define C_ 1024
#define H_ 16
#define D_ 64

// 0.125 * log2(e): attention scale folded into Q at projection time (R7b).
#define QSCALE 0.18033688011112042f

typedef float  f32x4  __attribute__((ext_vector_type(4)));
typedef __bf16 bf16x8 __attribute__((ext_vector_type(8)));
typedef __bf16 bf16x4 __attribute__((ext_vector_type(4)));
typedef __bf16 bf16x2 __attribute__((ext_vector_type(2)));
typedef unsigned uint2v __attribute__((ext_vector_type(2)));

typedef const __attribute__((address_space(1))) void gv_t;
typedef __attribute__((address_space(3))) void lds_t;

__device__ __forceinline__ void async_load16(const void* g, void* l) {
  __builtin_amdgcn_global_load_lds((gv_t*)g, (lds_t*)l, 16, 0, 0);
}

__device__ __forceinline__ float fast_exp2(float x) {
#if __has_builtin(__builtin_amdgcn_exp2f)
  return __builtin_amdgcn_exp2f(x);
#else
  return exp2f(x);
#endif
}

// v_permlane16_swap_b32: newA rows = [A0,B0,A2,B2], newB rows = [A1,B1,A3,B3]
__device__ __forceinline__ void pl16_swap(unsigned& a, unsigned& b) {
#if __has_builtin(__builtin_amdgcn_permlane16_swap)
  uint2v r = __builtin_amdgcn_permlane16_swap(a, b, false, false);
  a = r[0];
  b = r[1];
#else
  asm("v_permlane16_swap_b32 %0, %1" : "+v"(a), "+v"(b));
#endif
}

// ---------------- merged prep: cast x (blocks 0..4095) + W^T (4096..5119)
__global__ __launch_bounds__(256) void prep_kernel(
    const float* __restrict__ x, __bf16* __restrict__ xb,
    const float* __restrict__ W0, const float* __restrict__ W1,
    const float* __restrict__ W2, const float* __restrict__ W3,
    __bf16* __restrict__ wt) {
  __shared__ __align__(16) __bf16 sT[64][72];
  int l = blockIdx.x;
  int tid = threadIdx.x;
  if (l < 4096) {
    int i = (l * 256 + tid) * 8;  // exact: 4096*256*8 == B*T*C
    float4 a = *(const float4*)(x + i);
    float4 b = *(const float4*)(x + i + 4);
    bf16x8 o;
    o[0] = (__bf16)a.x; o[1] = (__bf16)a.y; o[2] = (__bf16)a.z; o[3] = (__bf16)a.w;
    o[4] = (__bf16)b.x; o[5] = (__bf16)b.y; o[6] = (__bf16)b.z; o[7] = (__bf16)b.w;
    *(bf16x8*)(xb + i) = o;
    return;
  }
  int t = l - 4096;                 // 0..1023
  int z = t >> 8;                   // 0..3
  int k0 = ((t >> 4) & 15) * 64;
  int n0 = (t & 15) * 64;
  const float* W = (z == 0) ? W0 : (z == 1) ? W1 : (z == 2) ? W2 : W3;
  __bf16* o = wt + (size_t)z * (C_ * C_);
#pragma unroll
  for (int i = 0; i < 4; i++) {
    int s = tid + i * 256;
    int kr = s >> 4, nc = (s & 15) * 4;
    float4 v = *(const float4*)&W[(size_t)(k0 + kr) * C_ + n0 + nc];
    bf16x4 tt;
    tt[0] = (__bf16)v.x; tt[1] = (__bf16)v.y; tt[2] = (__bf16)v.z; tt[3] = (__bf16)v.w;
    *(bf16x4*)&sT[kr][nc] = tt;
  }
  __syncthreads();
#pragma unroll
  for (int i = 0; i < 2; i++) {
    int s = tid + i * 256;
    int nr = s >> 3, kc = (s & 7) * 8;
    bf16x8 ov;
#pragma unroll
    for (int j = 0; j < 8; j++) ov[j] = sT[kc + j][nr];
    *(bf16x8*)&o[(size_t)(n0 + nr) * C_ + k0 + kc] = ov;
  }
}

// ------------------------------------------------ m97-style GEMM, B^T input
// C[M,BNtot] = (A[M,K](bf16) @ Bt[.,K](bf16)^T + bias) * scale
// Tile 128 x BN (BN = 128 or 64). EPI 0: row-major OutT. EPI 1: V-transpose
// into Vt[b,h,d,t] with the R6 kt-permutation (BN=128 only).
template <typename OutT, int EPI, int BN>
__device__ __forceinline__ void gemm_body(
    const __bf16* __restrict__ A, const __bf16* __restrict__ Bt,
    const float* __restrict__ bias, OutT* __restrict__ C, int N, int K,
    float scale, int m0, int n0) {
  __shared__ __align__(16) __bf16 sA[128 * 32];  // no pad: global_load_lds needs contig
  __shared__ __align__(16) __bf16 sB[BN * 32];
  constexpr int NTW = BN / 32;       // n-tiles per wave (4 or 2)
  constexpr int NBU = BN * 4 / 256;  // B staging units per thread (2 or 1)
  int tid = threadIdx.x, lane = tid & 63, wave = tid >> 6;
  int lr = lane & 15, quad = lane >> 4;
  int wm = (wave & 1) * 64, wn = (wave >> 1) * (BN / 2);

  const f32x4 zero = {0.f, 0.f, 0.f, 0.f};
  f32x4 acc[4][NTW];
#pragma unroll
  for (int i = 0; i < 4; i++)
#pragma unroll
    for (int j = 0; j < NTW; j++) acc[i][j] = zero;

  for (int k0 = 0; k0 < K; k0 += 32) {
    __syncthreads();
#pragma unroll
    for (int i = 0; i < 2; i++) {
      int s = tid + i * 256;
      int r = s >> 2, c8 = (s & 3) * 8;
      async_load16(A + (size_t)(m0 + r) * K + k0 + c8, &sA[s * 8]);
    }
#pragma unroll
    for (int i = 0; i < NBU; i++) {
      int s = tid + i * 256;
      int r = s >> 2, c8 = (s & 3) * 8;
      async_load16(Bt + (size_t)(n0 + r) * K + k0 + c8, &sB[s * 8]);
    }
    __syncthreads();
    bf16x8 af[4], bfr[NTW];
#pragma unroll
    for (int mt = 0; mt < 4; mt++)
      af[mt] = *(const bf16x8*)&sA[(wm + mt * 16 + lr) * 32 + quad * 8];
#pragma unroll
    for (int nt = 0; nt < NTW; nt++)
      bfr[nt] = *(const bf16x8*)&sB[(wn + nt * 16 + lr) * 32 + quad * 8];
#pragma unroll
    for (int mt = 0; mt < 4; mt++)
#pragma unroll
      for (int nt = 0; nt < NTW; nt++)
        acc[mt][nt] = __builtin_amdgcn_mfma_f32_16x16x32_bf16(
            af[mt], bfr[nt], acc[mt][nt], 0, 0, 0);
  }
  // C/D layout: col=lane&15 (n), row=mt*16+quad*4+reg (m)  [m89/m91]
  if (EPI == 0) {
#pragma unroll
    for (int mt = 0; mt < 4; mt++) {
#pragma unroll
      for (int nt = 0; nt < NTW; nt++) {
        int n = n0 + wn + nt * 16 + lr;
        float bv = bias[n];
#pragma unroll
        for (int r = 0; r < 4; r++) {
          int m = m0 + wm + mt * 16 + quad * 4 + r;
          C[(size_t)m * N + n] = (OutT)((acc[mt][nt][r] + bv) * scale);
        }
      }
    }
  } else {
    // V^T: Vt[(b*16+h)*64+d][t_permuted] = V[t][n=h*64+d] + bias
    int bb = m0 >> 11;               // m0 / T_ (tiles never straddle batches)
    int mloc0 = (m0 & (T_ - 1)) + wm;  // 64-aligned
    __bf16* Ct = (__bf16*)C;
#pragma unroll
    for (int mt = 0; mt < 4; mt++) {
      int pos = ((quad & 1) << 5) | ((((quad >> 1) << 1) | (mt & 1)) << 3) |
                ((mt >> 1) << 2);
#pragma unroll
      for (int nt = 0; nt < NTW; nt++) {
        int n = n0 + wn + nt * 16 + lr;
        float bv = bias[n];
        bf16x4 ov;
#pragma unroll
        for (int r = 0; r < 4; r++) ov[r] = (__bf16)(acc[mt][nt][r] + bv);
        *(bf16x4*)&Ct[((size_t)bb * C_ + n) * T_ + mloc0 + pos] = ov;
      }
    }
  }
}

// R10: 1-D grid 1536. xcd = l&7 owns 8 m-rows x 8 n-tiles per matrix z.
__global__ __launch_bounds__(256) void gemm_qkv_kernel(
    const __bf16* __restrict__ A, const __bf16* __restrict__ WT,
    const float* __restrict__ b0, const float* __restrict__ b1,
    const float* __restrict__ b2, __bf16* __restrict__ qkbase,
    __bf16* __restrict__ Vt) {
  int l = blockIdx.x;
  int xcd = l & 7;
  int idx = l >> 3;        // 0..191
  int z = idx >> 6;        // 0..2
  int rem = idx & 63;      // 0..63
  int m0 = (xcd * 8 + (rem >> 3)) * 128;
  int n0 = (rem & 7) * 128;
  if (z == 2) {
    gemm_body<__bf16, 1, 128>(A, WT + (size_t)2 * C_ * C_, b2, Vt, C_, C_,
                              1.0f, m0, n0);
  } else {
    const float* bias = (z == 0) ? b0 : b1;
    float scale = (z == 0) ? QSCALE : 1.0f;  // R7b: fold attn scale into Q
    gemm_body<__bf16, 0, 128>(A, WT + (size_t)z * C_ * C_, bias,
                              qkbase + (size_t)z * (B_ * T_) * C_, C_, C_,
                              scale, m0, n0);
  }
}

// R12: 128x64 tiles, grid 1024 = 4 blocks/CU.
__global__ __launch_bounds__(256) void gemm_proj_kernel(
    const __bf16* __restrict__ A, const __bf16* __restrict__ Bt,
    const float* __restrict__ bias, float* __restrict__ C) {
  int l = blockIdx.x;
  int xcd = l & 7;
  int idx = l >> 3;        // 0..127
  int m0 = (xcd * 8 + (idx >> 4)) * 128;  // 64 m-tiles
  int n0 = (idx & 15) * 64;               // 16 n-tiles of 64
  gemm_body<float, 0, 64>(A, Bt, bias, C, C_, C_, 1.0f, m0, n0);
}

// ----------------- attention, operand-swapped, no-max softmax, 64 q / wave
// R9 two-barrier body (VGPR-optimal). SPLIT=1: grid 512, full kt, bf16 out.
// SPLIT=2 (R14): grid 1024, half kt per block, f32 unnormalized partials.
template <int SPLIT>
__global__ __launch_bounds__(256) void attn_kernel(
    const __bf16* __restrict__ Q, const __bf16* __restrict__ K,
    const __bf16* __restrict__ Vt, __bf16* __restrict__ O,
    float* __restrict__ Opart, float* __restrict__ lpart) {
  __shared__ __align__(16) __bf16 sK[64 * 72];      // [kt][d]
  __shared__ __align__(16) __bf16 sV[64 * 72];      // [d][kt_permuted]
  int tid = threadIdx.x, wave = tid >> 6, lane = tid & 63;
  int lr = lane & 15, quad = lane >> 4;
  // XCD-clustered decode: l&7 = XCD class -> 8 bh per XCD (K/V 4MB = L2).
  int l = blockIdx.x;
  int bh = (l & 7) * 8 + ((l >> 3) & 7);
  int xbq = (l >> 6) & 7;
  int half = (SPLIT == 2) ? (l >> 9) : 0;
  int kt0 = half * (T_ / SPLIT);
  int kt1 = kt0 + T_ / SPLIT;
  int b = bh >> 4, h = bh & 15;
  int qw = xbq * 256 + wave * 64;

  bf16x8 aq[4][2];
#pragma unroll
  for (int s = 0; s < 4; s++) {
    const __bf16* qp =
        Q + ((size_t)(b * T_ + qw + s * 16 + lr)) * C_ + h * D_ + quad * 8;
    aq[s][0] = *(const bf16x8*)qp;
    aq[s][1] = *(const bf16x8*)(qp + 32);
  }

  bf16x8 onesf;
#pragma unroll
  for (int j = 0; j < 8; j++) onesf[j] = (__bf16)1.0f;

  const f32x4 zero = {0.f, 0.f, 0.f, 0.f};
  f32x4 accO[4][4];
  f32x4 accL[4] = {zero, zero, zero, zero};
#pragma unroll
  for (int s = 0; s < 4; s++)
#pragma unroll
    for (int d = 0; d < 4; d++) accO[s][d] = zero;

  int srow[2], sc8[2];
#pragma unroll
  for (int i = 0; i < 2; i++) {
    int s = tid + i * 256;
    srow[i] = s >> 3;
    sc8[i] = (s & 7) * 8;
  }

  bf16x8 kreg[2], vreg[2];
#pragma unroll
  for (int i = 0; i < 2; i++) {
    kreg[i] = *(const bf16x8*)(K + ((size_t)(b * T_ + kt0 + srow[i])) * C_ + h * D_ + sc8[i]);
    vreg[i] = *(const bf16x8*)(Vt + ((size_t)(bh * D_ + srow[i])) * T_ + kt0 + sc8[i]);
  }

  for (int k0 = kt0; k0 < kt1; k0 += 64) {
    // barrier A: protect previous chunk's readers from the writes below.
    __builtin_amdgcn_sched_barrier(0);
    __builtin_amdgcn_s_barrier();
    __builtin_amdgcn_sched_barrier(0);
#pragma unroll
    for (int i = 0; i < 2; i++) {
      *(bf16x8*)&sK[srow[i] * 72 + sc8[i]] = kreg[i];
      *(bf16x8*)&sV[srow[i] * 72 + sc8[i]] = vreg[i];
    }
    // barrier B: writes visible to all waves; no vmcnt drain (R9a).
    __builtin_amdgcn_sched_barrier(0);
    asm volatile("s_waitcnt lgkmcnt(0)" ::: "memory");
    __builtin_amdgcn_s_barrier();
    __builtin_amdgcn_sched_barrier(0);

    if (k0 + 64 < kt1) {
      int kn = k0 + 64;
#pragma unroll
      for (int i = 0; i < 2; i++) {
        kreg[i] = *(const bf16x8*)(K + ((size_t)(b * T_ + kn + srow[i])) * C_ + h * D_ + sc8[i]);
        vreg[i] = *(const bf16x8*)(Vt + ((size_t)(bh * D_ + srow[i])) * T_ + kn + sc8[i]);
      }
    }

    // K fragments: 8 LDS reads per chunk, shared by all 4 q-sets (R7a).
    bf16x8 bkf[4][2];
#pragma unroll
    for (int nt = 0; nt < 4; nt++) {
      bkf[nt][0] = *(const bf16x8*)&sK[(nt * 16 + lr) * 72 + quad * 8];
      bkf[nt][1] = *(const bf16x8*)&sK[(nt * 16 + lr) * 72 + 32 + quad * 8];
    }

    bf16x8 bpA[4], bpB[4];
#pragma unroll
    for (int s = 0; s < 4; s++) {
      unsigned pw[4][2];
#pragma unroll
      for (int nt = 0; nt < 4; nt++) {
        f32x4 z = zero;
        z = __builtin_amdgcn_mfma_f32_16x16x32_bf16(bkf[nt][0], aq[s][0], z, 0, 0, 0);
        z = __builtin_amdgcn_mfma_f32_16x16x32_bf16(bkf[nt][1], aq[s][1], z, 0, 0, 0);
        union { bf16x2 h2; unsigned u; } t0, t1;
        t0.h2[0] = (__bf16)fast_exp2(z[0]);
        t0.h2[1] = (__bf16)fast_exp2(z[1]);
        t1.h2[0] = (__bf16)fast_exp2(z[2]);
        t1.h2[1] = (__bf16)fast_exp2(z[3]);
        pw[nt][0] = t0.u;
        pw[nt][1] = t1.u;
      }
      unsigned a0 = pw[0][0], b0 = pw[1][0]; pl16_swap(a0, b0);
      unsigned a1 = pw[0][1], b1 = pw[1][1]; pl16_swap(a1, b1);
      unsigned a2 = pw[2][0], b2 = pw[3][0]; pl16_swap(a2, b2);
      unsigned a3 = pw[2][1], b3 = pw[3][1]; pl16_swap(a3, b3);
      union { unsigned u[4]; bf16x8 v; } pA, pB;
      pA.u[0] = a0; pA.u[1] = a1; pA.u[2] = a2; pA.u[3] = a3;
      pB.u[0] = b0; pB.u[1] = b1; pB.u[2] = b2; pB.u[3] = b3;
      bpA[s] = pA.v;
      bpB[s] = pB.v;
      accL[s] = __builtin_amdgcn_mfma_f32_16x16x32_bf16(onesf, bpA[s], accL[s], 0, 0, 0);
      accL[s] = __builtin_amdgcn_mfma_f32_16x16x32_bf16(onesf, bpB[s], accL[s], 0, 0, 0);
    }
#pragma unroll
    for (int dt = 0; dt < 4; dt++) {
      bf16x8 av0 = *(const bf16x8*)&sV[(dt * 16 + lr) * 72 + quad * 8];
      bf16x8 av1 = *(const bf16x8*)&sV[(dt * 16 + lr) * 72 + 32 + quad * 8];
#pragma unroll
      for (int s = 0; s < 4; s++) {
        accO[s][dt] = __builtin_amdgcn_mfma_f32_16x16x32_bf16(av0, bpA[s], accO[s][dt], 0, 0, 0);
        accO[s][dt] = __builtin_amdgcn_mfma_f32_16x16x32_bf16(av1, bpB[s], accO[s][dt], 0, 0, 0);
      }
    }
  }

  if (SPLIT == 1) {
#pragma unroll
    for (int s = 0; s < 4; s++) {
      float inv = 1.0f / accL[s][0];
      __bf16* op =
          O + ((size_t)(b * T_ + qw + s * 16 + lr)) * C_ + h * D_ + quad * 4;
#pragma unroll
      for (int dt = 0; dt < 4; dt++) {
        bf16x4 ov;
#pragma unroll
        for (int r = 0; r < 4; r++) ov[r] = (__bf16)(accO[s][dt][r] * inv);
        *(bf16x4*)&op[dt * 16] = ov;
      }
    }
  } else {
    // R14: unnormalized f32 partials; l once per q (accL same across quads).
    float* opb = Opart + (size_t)half * (B_ * T_ * C_);
#pragma unroll
    for (int s = 0; s < 4; s++) {
      float* op = opb + ((size_t)(b * T_ + qw + s * 16 + lr)) * C_ + h * D_ + quad * 4;
#pragma unroll
      for (int dt = 0; dt < 4; dt++) *(f32x4*)&op[dt * 16] = accO[s][dt];
      if (quad == 0)
        lpart[(size_t)half * (64 * T_) + (size_t)bh * T_ + qw + s * 16 + lr] =
            accL[s][0];
    }
  }
}

// R14 combine: attnb = (O0+O1)/(l0+l1), 16M elems, memory-bound.
__global__ __launch_bounds__(256) void attn_combine(
    const float* __restrict__ Opart, const float* __restrict__ lpart,
    __bf16* __restrict__ O) {
  int e8 = blockIdx.x * 256 + threadIdx.x;  // 2,097,152 units of 8 elems
  size_t e = (size_t)e8 * 8;
  int row = e8 >> 7;           // e / 1024 = b*T+t
  int c = (int)(e & 1023);
  int bq = row >> 11;          // batch
  int t = row & (T_ - 1);
  int h = c >> 6;
  float l0 = lpart[(size_t)(bq * 16 + h) * T_ + t];
  float l1 = lpart[(size_t)(64 * T_) + (size_t)(bq * 16 + h) * T_ + t];
  float inv = 1.0f / (l0 + l1);
  const float* p0 = Opart + e;
  const float* p1 = Opart + (size_t)(B_ * T_ * C_) + e;
  f32x4 a0 = *(const f32x4*)p0, a1 = *(const f32x4*)(p0 + 4);
  f32x4 b0 = *(const f32x4*)p1, b1 = *(const f32x4*)(p1 + 4);
  bf16x8 o;
#pragma unroll
  for (int j = 0; j < 4; j++) {
    o[j] = (__bf16)((a0[j] + b0[j]) * inv);
    o[j + 4] = (__bf16)((a1[j] + b1[j]) * inv);
  }
  *(bf16x8*)(O + e) = o;
}

// ------------------------------------------------------------------ launch
extern "C" void kernel_launch(void* const* d_in, const int* in_sizes, int n_in,
                              void* d_out, int out_size, void* d_ws, size_t ws_size,
                              hipStream_t stream) {
  const float* x  = (const float*)d_in[0];
  const float* Wq = (const float*)d_in[1];
  const float* bq = (const float*)d_in[2];
  const float* Wk = (const float*)d_in[3];
  const float* bk = (const float*)d_in[4];
  const float* Wv = (const float*)d_in[5];
  const float* bv = (const float*)d_in[6];
  const float* Wp = (const float*)d_in[7];
  const float* bp = (const float*)d_in[8];
  float* out = (float*)d_out;

  char* ws = (char*)d_ws;
  const size_t MB = 1024 * 1024;
  __bf16* xb    = (__bf16*)(ws + 0 * MB);   // 16 MB
  __bf16* WT    = (__bf16*)(ws + 16 * MB);  // 8 MB
  __bf16* Qb    = (__bf16*)(ws + 24 * MB);  // Q 16 MB (pre-scaled by QSCALE)
  __bf16* Kb    = Qb + (size_t)(B_ * T_) * C_;   // K 16 MB
  __bf16* Vt    = Kb + (size_t)(B_ * T_) * C_;   // V^T 16 MB (R6-permuted)
  __bf16* attnb = (__bf16*)(ws + 72 * MB);  // 16 MB
  float*  Opart = (float*)(ws + 88 * MB);   // 64 MB (R14 partials)
  float*  lpart = (float*)(ws + 152 * MB);  // 1 MB; total 153 MB
  __bf16* WpT   = WT + (size_t)3 * C_ * C_;

  bool split = ws_size >= 154 * MB;

  prep_kernel<<<dim3(5120), dim3(256), 0, stream>>>(x, xb, Wq, Wk, Wv, Wp, WT);
  gemm_qkv_kernel<<<dim3(1536), dim3(256), 0, stream>>>(xb, WT, bq, bk, bv, Qb, Vt);
  if (split) {
    attn_kernel<2><<<dim3(1024), dim3(256), 0, stream>>>(Qb, Kb, Vt, attnb,
                                                         Opart, lpart);
    attn_combine<<<dim3(8192), dim3(256), 0, stream>>>(Opart, lpart, attnb);
  } else {
    attn_kernel<1><<<dim3(512), dim3(256), 0, stream>>>(Qb, Kb, Vt, attnb,
                                                        nullptr, nullptr);
  }
  gemm_proj_kernel<<<dim3(1024), dim3(256), 0, stream>>>(attnb, WpT, bp, out);
}

// Round 11
// 265.691 us; speedup vs baseline: 1.1488x; 1.1364x over previous
//
#include <hip/hip_runtime.h>

// MultiHeadAttention: B=4 T=2048 C=1024 H=16 D=64, fp32 in/out, bf16 MFMA internally.
//
// Pipeline (all on `stream`):
//   1. prep_kernel:      cast x -> bf16 AND Wq/Wk/Wv/Wp -> W^T bf16 (merged)
//   2. gemm_qkv:         Q/K = xb @ W^T + b (bf16); Q pre-scaled by
//                        0.125*log2(e) (R7); V written TRANSPOSED as Vt
//                        [b,h,d,t] (kt-permuted, R6); XCD-clustered grid (R10)
//   3. attn_kernel:      flash attention, operand-swapped, 64 q/wave (R7),
//                        XCD-clustered grid + raw two-barrier body (R9)
//   4. gemm_proj:        out = attn @ Wp^T + bp, fp32; 128x64 tiles (R12)
//
// R15 = best-proven combination after the R8/R11/R13/R14 structural probes
// all regressed or nulled:
//   - attn: R9 body exactly (85.5us measured; VGPR 116, 2 barriers/chunk).
//     PROVEN NEGATIVE on this body: setprio (+3.6us, R12), KVBLK=128 dbuf
//     (114us, R11), KVBLK=64 single-barrier dbuf (122us, R13), split-kt x2
//     (occupancy did NOT rise: scheduler won't stack >2 of these blocks/CU;
//     +34us total, R14). attn is issue-bound: MFMA 36 + VALU 45 + LDS ~15%.
//   - GEMMs: m97 128-tile 2-barrier structure; 256^2 8-phase nulled at this
//     shape (R8: proj grid 128 blocks = half the CUs idle).
//   - R6: P LDS round-trip eliminated via bf16x2 pack + permlane16_swap;
//     V^T stored kt-permuted: pos = (quad&1)<<5 | (((quad>>1)<<1|(mt&1))<<3)
//     | ((mt>>1)<<2) (+r) per 64-aligned t-block.
//   - R7: 64 q/wave (4 q-sets share K/V frags); logit scale folded into Q.
//   - R9b: XCD-clustered attn grid (FETCH 139->24.6MB; K/V L2-resident).
//   - R12: proj 128x64 tiles -> 1024 blocks = 4/CU (~+4us vs 2/CU).

#define B_ 4
#define T_ 2048
#define C_ 1024
#define H_ 16
#define D_ 64

// 0.125 * log2(e): attention scale folded into Q at projection time (R7b).
#define QSCALE 0.18033688011112042f

typedef float  f32x4  __attribute__((ext_vector_type(4)));
typedef __bf16 bf16x8 __attribute__((ext_vector_type(8)));
typedef __bf16 bf16x4 __attribute__((ext_vector_type(4)));
typedef __bf16 bf16x2 __attribute__((ext_vector_type(2)));
typedef unsigned uint2v __attribute__((ext_vector_type(2)));

typedef const __attribute__((address_space(1))) void gv_t;
typedef __attribute__((address_space(3))) void lds_t;

__device__ __forceinline__ void async_load16(const void* g, void* l) {
  __builtin_amdgcn_global_load_lds((gv_t*)g, (lds_t*)l, 16, 0, 0);
}

__device__ __forceinline__ float fast_exp2(float x) {
#if __has_builtin(__builtin_amdgcn_exp2f)
  return __builtin_amdgcn_exp2f(x);
#else
  return exp2f(x);
#endif
}

// v_permlane16_swap_b32: newA rows = [A0,B0,A2,B2], newB rows = [A1,B1,A3,B3]
__device__ __forceinline__ void pl16_swap(unsigned& a, unsigned& b) {
#if __has_builtin(__builtin_amdgcn_permlane16_swap)
  uint2v r = __builtin_amdgcn_permlane16_swap(a, b, false, false);
  a = r[0];
  b = r[1];
#else
  asm("v_permlane16_swap_b32 %0, %1" : "+v"(a), "+v"(b));
#endif
}

// ---------------- merged prep: cast x (blocks 0..4095) + W^T (4096..5119)
__global__ __launch_bounds__(256) void prep_kernel(
    const float* __restrict__ x, __bf16* __restrict__ xb,
    const float* __restrict__ W0, const float* __restrict__ W1,
    const float* __restrict__ W2, const float* __restrict__ W3,
    __bf16* __restrict__ wt) {
  __shared__ __align__(16) __bf16 sT[64][72];
  int l = blockIdx.x;
  int tid = threadIdx.x;
  if (l < 4096) {
    int i = (l * 256 + tid) * 8;  // exact: 4096*256*8 == B*T*C
    float4 a = *(const float4*)(x + i);
    float4 b = *(const float4*)(x + i + 4);
    bf16x8 o;
    o[0] = (__bf16)a.x; o[1] = (__bf16)a.y; o[2] = (__bf16)a.z; o[3] = (__bf16)a.w;
    o[4] = (__bf16)b.x; o[5] = (__bf16)b.y; o[6] = (__bf16)b.z; o[7] = (__bf16)b.w;
    *(bf16x8*)(xb + i) = o;
    return;
  }
  int t = l - 4096;                 // 0..1023
  int z = t >> 8;                   // 0..3
  int k0 = ((t >> 4) & 15) * 64;
  int n0 = (t & 15) * 64;
  const float* W = (z == 0) ? W0 : (z == 1) ? W1 : (z == 2) ? W2 : W3;
  __bf16* o = wt + (size_t)z * (C_ * C_);
#pragma unroll
  for (int i = 0; i < 4; i++) {
    int s = tid + i * 256;
    int kr = s >> 4, nc = (s & 15) * 4;
    float4 v = *(const float4*)&W[(size_t)(k0 + kr) * C_ + n0 + nc];
    bf16x4 tt;
    tt[0] = (__bf16)v.x; tt[1] = (__bf16)v.y; tt[2] = (__bf16)v.z; tt[3] = (__bf16)v.w;
    *(bf16x4*)&sT[kr][nc] = tt;
  }
  __syncthreads();
#pragma unroll
  for (int i = 0; i < 2; i++) {
    int s = tid + i * 256;
    int nr = s >> 3, kc = (s & 7) * 8;
    bf16x8 ov;
#pragma unroll
    for (int j = 0; j < 8; j++) ov[j] = sT[kc + j][nr];
    *(bf16x8*)&o[(size_t)(n0 + nr) * C_ + k0 + kc] = ov;
  }
}

// ------------------------------------------------ m97-style GEMM, B^T input
// C[M,BNtot] = (A[M,K](bf16) @ Bt[.,K](bf16)^T + bias) * scale
// Tile 128 x BN (BN = 128 or 64). EPI 0: row-major OutT. EPI 1: V-transpose
// into Vt[b,h,d,t] with the R6 kt-permutation (BN=128 only).
template <typename OutT, int EPI, int BN>
__device__ __forceinline__ void gemm_body(
    const __bf16* __restrict__ A, const __bf16* __restrict__ Bt,
    const float* __restrict__ bias, OutT* __restrict__ C, int N, int K,
    float scale, int m0, int n0) {
  __shared__ __align__(16) __bf16 sA[128 * 32];  // no pad: global_load_lds needs contig
  __shared__ __align__(16) __bf16 sB[BN * 32];
  constexpr int NTW = BN / 32;       // n-tiles per wave (4 or 2)
  constexpr int NBU = BN * 4 / 256;  // B staging units per thread (2 or 1)
  int tid = threadIdx.x, lane = tid & 63, wave = tid >> 6;
  int lr = lane & 15, quad = lane >> 4;
  int wm = (wave & 1) * 64, wn = (wave >> 1) * (BN / 2);

  const f32x4 zero = {0.f, 0.f, 0.f, 0.f};
  f32x4 acc[4][NTW];
#pragma unroll
  for (int i = 0; i < 4; i++)
#pragma unroll
    for (int j = 0; j < NTW; j++) acc[i][j] = zero;

  for (int k0 = 0; k0 < K; k0 += 32) {
    __syncthreads();
#pragma unroll
    for (int i = 0; i < 2; i++) {
      int s = tid + i * 256;
      int r = s >> 2, c8 = (s & 3) * 8;
      async_load16(A + (size_t)(m0 + r) * K + k0 + c8, &sA[s * 8]);
    }
#pragma unroll
    for (int i = 0; i < NBU; i++) {
      int s = tid + i * 256;
      int r = s >> 2, c8 = (s & 3) * 8;
      async_load16(Bt + (size_t)(n0 + r) * K + k0 + c8, &sB[s * 8]);
    }
    __syncthreads();
    bf16x8 af[4], bfr[NTW];
#pragma unroll
    for (int mt = 0; mt < 4; mt++)
      af[mt] = *(const bf16x8*)&sA[(wm + mt * 16 + lr) * 32 + quad * 8];
#pragma unroll
    for (int nt = 0; nt < NTW; nt++)
      bfr[nt] = *(const bf16x8*)&sB[(wn + nt * 16 + lr) * 32 + quad * 8];
#pragma unroll
    for (int mt = 0; mt < 4; mt++)
#pragma unroll
      for (int nt = 0; nt < NTW; nt++)
        acc[mt][nt] = __builtin_amdgcn_mfma_f32_16x16x32_bf16(
            af[mt], bfr[nt], acc[mt][nt], 0, 0, 0);
  }
  // C/D layout: col=lane&15 (n), row=mt*16+quad*4+reg (m)  [m89/m91]
  if (EPI == 0) {
#pragma unroll
    for (int mt = 0; mt < 4; mt++) {
#pragma unroll
      for (int nt = 0; nt < NTW; nt++) {
        int n = n0 + wn + nt * 16 + lr;
        float bv = bias[n];
#pragma unroll
        for (int r = 0; r < 4; r++) {
          int m = m0 + wm + mt * 16 + quad * 4 + r;
          C[(size_t)m * N + n] = (OutT)((acc[mt][nt][r] + bv) * scale);
        }
      }
    }
  } else {
    // V^T: Vt[(b*16+h)*64+d][t_permuted] = V[t][n=h*64+d] + bias
    int bb = m0 >> 11;               // m0 / T_ (tiles never straddle batches)
    int mloc0 = (m0 & (T_ - 1)) + wm;  // 64-aligned
    __bf16* Ct = (__bf16*)C;
#pragma unroll
    for (int mt = 0; mt < 4; mt++) {
      int pos = ((quad & 1) << 5) | ((((quad >> 1) << 1) | (mt & 1)) << 3) |
                ((mt >> 1) << 2);
#pragma unroll
      for (int nt = 0; nt < NTW; nt++) {
        int n = n0 + wn + nt * 16 + lr;
        float bv = bias[n];
        bf16x4 ov;
#pragma unroll
        for (int r = 0; r < 4; r++) ov[r] = (__bf16)(acc[mt][nt][r] + bv);
        *(bf16x4*)&Ct[((size_t)bb * C_ + n) * T_ + mloc0 + pos] = ov;
      }
    }
  }
}

// R10: 1-D grid 1536. xcd = l&7 owns 8 m-rows x 8 n-tiles per matrix z.
__global__ __launch_bounds__(256) void gemm_qkv_kernel(
    const __bf16* __restrict__ A, const __bf16* __restrict__ WT,
    const float* __restrict__ b0, const float* __restrict__ b1,
    const float* __restrict__ b2, __bf16* __restrict__ qkbase,
    __bf16* __restrict__ Vt) {
  int l = blockIdx.x;
  int xcd = l & 7;
  int idx = l >> 3;        // 0..191
  int z = idx >> 6;        // 0..2
  int rem = idx & 63;      // 0..63
  int m0 = (xcd * 8 + (rem >> 3)) * 128;
  int n0 = (rem & 7) * 128;
  if (z == 2) {
    gemm_body<__bf16, 1, 128>(A, WT + (size_t)2 * C_ * C_, b2, Vt, C_, C_,
                              1.0f, m0, n0);
  } else {
    const float* bias = (z == 0) ? b0 : b1;
    float scale = (z == 0) ? QSCALE : 1.0f;  // R7b: fold attn scale into Q
    gemm_body<__bf16, 0, 128>(A, WT + (size_t)z * C_ * C_, bias,
                              qkbase + (size_t)z * (B_ * T_) * C_, C_, C_,
                              scale, m0, n0);
  }
}

// R12: 128x64 tiles, grid 1024 = 4 blocks/CU.
__global__ __launch_bounds__(256) void gemm_proj_kernel(
    const __bf16* __restrict__ A, const __bf16* __restrict__ Bt,
    const float* __restrict__ bias, float* __restrict__ C) {
  int l = blockIdx.x;
  int xcd = l & 7;
  int idx = l >> 3;        // 0..127
  int m0 = (xcd * 8 + (idx >> 4)) * 128;  // 64 m-tiles
  int n0 = (idx & 15) * 64;               // 16 n-tiles of 64
  gemm_body<float, 0, 64>(A, Bt, bias, C, C_, C_, 1.0f, m0, n0);
}

// ----------------- attention, operand-swapped, no-max softmax, 64 q / wave
// grid 512 (1-D, XCD-clustered), 256 thr. R9 two-barrier body, no setprio.
__global__ __launch_bounds__(256) void attn_kernel(
    const __bf16* __restrict__ Q, const __bf16* __restrict__ K,
    const __bf16* __restrict__ Vt, __bf16* __restrict__ O) {
  __shared__ __align__(16) __bf16 sK[64 * 72];      // [kt][d]
  __shared__ __align__(16) __bf16 sV[64 * 72];      // [d][kt_permuted]
  int tid = threadIdx.x, wave = tid >> 6, lane = tid & 63;
  int lr = lane & 15, quad = lane >> 4;
  // R9b: XCD-clustered decode. l%8 = XCD class -> 8 bh per XCD (K/V = 4MB,
  // L2-resident); same-CU blocks (l, l+256) share bh (L1 reuse).
  int l = blockIdx.x;
  int bh = (l & 7) * 8 + ((l >> 3) & 7);
  int xbq = l >> 6;  // 0..7
  int b = bh >> 4, h = bh & 15;
  int qw = xbq * 256 + wave * 64;

  bf16x8 aq[4][2];
#pragma unroll
  for (int s = 0; s < 4; s++) {
    const __bf16* qp =
        Q + ((size_t)(b * T_ + qw + s * 16 + lr)) * C_ + h * D_ + quad * 8;
    aq[s][0] = *(const bf16x8*)qp;
    aq[s][1] = *(const bf16x8*)(qp + 32);
  }

  bf16x8 onesf;
#pragma unroll
  for (int j = 0; j < 8; j++) onesf[j] = (__bf16)1.0f;

  const f32x4 zero = {0.f, 0.f, 0.f, 0.f};
  f32x4 accO[4][4];
  f32x4 accL[4] = {zero, zero, zero, zero};
#pragma unroll
  for (int s = 0; s < 4; s++)
#pragma unroll
    for (int d = 0; d < 4; d++) accO[s][d] = zero;

  int srow[2], sc8[2];
#pragma unroll
  for (int i = 0; i < 2; i++) {
    int s = tid + i * 256;
    srow[i] = s >> 3;
    sc8[i] = (s & 7) * 8;
  }

  bf16x8 kreg[2], vreg[2];
#pragma unroll
  for (int i = 0; i < 2; i++) {
    kreg[i] = *(const bf16x8*)(K + ((size_t)(b * T_ + srow[i])) * C_ + h * D_ + sc8[i]);
    vreg[i] = *(const bf16x8*)(Vt + ((size_t)(bh * D_ + srow[i])) * T_ + sc8[i]);
  }

  for (int k0 = 0; k0 < T_; k0 += 64) {
    // barrier A: protect previous chunk's readers from the writes below.
    __builtin_amdgcn_sched_barrier(0);
    __builtin_amdgcn_s_barrier();
    __builtin_amdgcn_sched_barrier(0);
#pragma unroll
    for (int i = 0; i < 2; i++) {
      *(bf16x8*)&sK[srow[i] * 72 + sc8[i]] = kreg[i];
      *(bf16x8*)&sV[srow[i] * 72 + sc8[i]] = vreg[i];
    }
    // barrier B: writes visible to all waves; no vmcnt drain (R9a).
    __builtin_amdgcn_sched_barrier(0);
    asm volatile("s_waitcnt lgkmcnt(0)" ::: "memory");
    __builtin_amdgcn_s_barrier();
    __builtin_amdgcn_sched_barrier(0);

    if (k0 + 64 < T_) {
      int kn = k0 + 64;
#pragma unroll
      for (int i = 0; i < 2; i++) {
        kreg[i] = *(const bf16x8*)(K + ((size_t)(b * T_ + kn + srow[i])) * C_ + h * D_ + sc8[i]);
        vreg[i] = *(const bf16x8*)(Vt + ((size_t)(bh * D_ + srow[i])) * T_ + kn + sc8[i]);
      }
    }

    // K fragments: 8 LDS reads per chunk, shared by all 4 q-sets (R7a).
    bf16x8 bkf[4][2];
#pragma unroll
    for (int nt = 0; nt < 4; nt++) {
      bkf[nt][0] = *(const bf16x8*)&sK[(nt * 16 + lr) * 72 + quad * 8];
      bkf[nt][1] = *(const bf16x8*)&sK[(nt * 16 + lr) * 72 + 32 + quad * 8];
    }

    bf16x8 bpA[4], bpB[4];
#pragma unroll
    for (int s = 0; s < 4; s++) {
      unsigned pw[4][2];
#pragma unroll
      for (int nt = 0; nt < 4; nt++) {
        f32x4 z = zero;
        z = __builtin_amdgcn_mfma_f32_16x16x32_bf16(bkf[nt][0], aq[s][0], z, 0, 0, 0);
        z = __builtin_amdgcn_mfma_f32_16x16x32_bf16(bkf[nt][1], aq[s][1], z, 0, 0, 0);
        union { bf16x2 h2; unsigned u; } t0, t1;
        t0.h2[0] = (__bf16)fast_exp2(z[0]);
        t0.h2[1] = (__bf16)fast_exp2(z[1]);
        t1.h2[0] = (__bf16)fast_exp2(z[2]);
        t1.h2[1] = (__bf16)fast_exp2(z[3]);
        pw[nt][0] = t0.u;
        pw[nt][1] = t1.u;
      }
      unsigned a0 = pw[0][0], b0 = pw[1][0]; pl16_swap(a0, b0);
      unsigned a1 = pw[0][1], b1 = pw[1][1]; pl16_swap(a1, b1);
      unsigned a2 = pw[2][0], b2 = pw[3][0]; pl16_swap(a2, b2);
      unsigned a3 = pw[2][1], b3 = pw[3][1]; pl16_swap(a3, b3);
      union { unsigned u[4]; bf16x8 v; } pA, pB;
      pA.u[0] = a0; pA.u[1] = a1; pA.u[2] = a2; pA.u[3] = a3;
      pB.u[0] = b0; pB.u[1] = b1; pB.u[2] = b2; pB.u[3] = b3;
      bpA[s] = pA.v;
      bpB[s] = pB.v;
      accL[s] = __builtin_amdgcn_mfma_f32_16x16x32_bf16(onesf, bpA[s], accL[s], 0, 0, 0);
      accL[s] = __builtin_amdgcn_mfma_f32_16x16x32_bf16(onesf, bpB[s], accL[s], 0, 0, 0);
    }
#pragma unroll
    for (int dt = 0; dt < 4; dt++) {
      bf16x8 av0 = *(const bf16x8*)&sV[(dt * 16 + lr) * 72 + quad * 8];
      bf16x8 av1 = *(const bf16x8*)&sV[(dt * 16 + lr) * 72 + 32 + quad * 8];
#pragma unroll
      for (int s = 0; s < 4; s++) {
        accO[s][dt] = __builtin_amdgcn_mfma_f32_16x16x32_bf16(av0, bpA[s], accO[s][dt], 0, 0, 0);
        accO[s][dt] = __builtin_amdgcn_mfma_f32_16x16x32_bf16(av1, bpB[s], accO[s][dt], 0, 0, 0);
      }
    }
  }

#pragma unroll
  for (int s = 0; s < 4; s++) {
    float inv = 1.0f / accL[s][0];
    __bf16* op =
        O + ((size_t)(b * T_ + qw + s * 16 + lr)) * C_ + h * D_ + quad * 4;
#pragma unroll
    for (int dt = 0; dt < 4; dt++) {
      bf16x4 ov;
#pragma unroll
      for (int r = 0; r < 4; r++) ov[r] = (__bf16)(accO[s][dt][r] * inv);
      *(bf16x4*)&op[dt * 16] = ov;
    }
  }
}

// ------------------------------------------------------------------ launch
extern "C" void kernel_launch(void* const* d_in, const int* in_sizes, int n_in,
                              void* d_out, int out_size, void* d_ws, size_t ws_size,
                              hipStream_t stream) {
  const float* x  = (const float*)d_in[0];
  const float* Wq = (const float*)d_in[1];
  const float* bq = (const float*)d_in[2];
  const float* Wk = (const float*)d_in[3];
  const float* bk = (const float*)d_in[4];
  const float* Wv = (const float*)d_in[5];
  const float* bv = (const float*)d_in[6];
  const float* Wp = (const float*)d_in[7];
  const float* bp = (const float*)d_in[8];
  float* out = (float*)d_out;

  char* ws = (char*)d_ws;
  const size_t MB = 1024 * 1024;
  __bf16* xb    = (__bf16*)(ws + 0 * MB);   // 16 MB
  __bf16* WT    = (__bf16*)(ws + 16 * MB);  // 8 MB
  __bf16* Qb    = (__bf16*)(ws + 24 * MB);  // Q 16 MB (pre-scaled by QSCALE)
  __bf16* Kb    = Qb + (size_t)(B_ * T_) * C_;   // K 16 MB
  __bf16* Vt    = Kb + (size_t)(B_ * T_) * C_;   // V^T 16 MB (R6-permuted)
  __bf16* attnb = (__bf16*)(ws + 72 * MB);  // 16 MB; total 88 MB
  __bf16* WpT   = WT + (size_t)3 * C_ * C_;

  prep_kernel<<<dim3(5120), dim3(256), 0, stream>>>(x, xb, Wq, Wk, Wv, Wp, WT);
  gemm_qkv_kernel<<<dim3(1536), dim3(256), 0, stream>>>(xb, WT, bq, bk, bv, Qb, Vt);
  attn_kernel<<<dim3(512), dim3(256), 0, stream>>>(Qb, Kb, Vt, attnb);
  gemm_proj_kernel<<<dim3(1024), dim3(256), 0, stream>>>(attnb, WpT, bp, out);
}